// Round 2
// baseline (431.231 us; speedup 1.0000x reference)
//
#include <hip/hip_runtime.h>
#include <math.h>

// Problem constants (fixed by reference)
#define B_TOT   256
#define N_TOT   2304
#define IN_DIM  8
#define NC      10      // NUM_CLASSES
#define OD      16      // OUT_DIM
#define CD      160     // NC*OD
#define RBIAS   0.1f

// Tiling: wave-per-class layout. Block = 10 waves (c=0..9) × 64 lanes (b).
#define BTILE    64                      // b per block (= wave lanes)
#define NS       192                     // n-slices; grid = 4*192 = 768 = 3 blk/CU
#define NPB      (N_TOT / NS)            // 12 n per block
#define NTHREADS 640                     // 10 waves
#define XR       (NPB * IN_DIM + 4)      // 100: x row stride
#define LB       72                      // logit board row stride
#define NF4      (B_TOT * CD / 4)        // 10240 float4 per partial slab

// XCD swizzle (kept from R1: FETCH 55.5->21.4 MB, W reads now L2-local)
#define NXCD     8
#define YPX      (NS / NXCD)             // 24

// Reduce: 1280 blocks × 256 thr = 5 blk/CU balanced
#define RCOLS    8                       // float4-columns per reduce block
#define RGRPS    32                      // y-groups per reduce block
#define RYPER    (NS / RGRPS)            // 6 slabs per (col, grp) thread

// ===== Routing round. R2 change: W loads forced onto the VECTOR memory path.
// R1 post-mortem: wave-uniform W addresses lowered to s_load chains through
// the scalar K$; round-0 ran at VALUBusy 20.6% with the same 52us as rounds
// 1/2 -> ~80% scalar-load stall, insensitive to data location (HBM vs L2).
// An opaque-zero VGPR in the W pointer defeats uniformity analysis ->
// global_load_dwordx4 (identical lane addrs coalesce to 1 txn; W is
// L1-resident across the 10 sharing waves; deep vmem queues pipeline).
template <int FIRST>
__global__ __launch_bounds__(NTHREADS) void routing_round(
    const float* __restrict__ x,      // [B, N, 8]
    const float* __restrict__ W,      // [N, 8, 160]
    const float* __restrict__ S_acc,  // [B, 160]
    float* __restrict__ part)         // [NS, B, 160]
{
    __shared__ float sh_x[BTILE * XR];            // 25.6 KB
    __shared__ float sh_lg[2][NC * LB];           // 5.8 KB

    const int tid = threadIdx.x;

    // XCD-aware remap (bijective, 768 % 8 == 0)
    const int bid  = blockIdx.y * gridDim.x + blockIdx.x;   // 0..767
    const int xcd  = bid & (NXCD - 1);
    const int slot = bid >> 3;                              // 0..95
    const int b0   = (slot & 3) * BTILE;
    const int ySlab = xcd * YPX + (slot >> 2);              // logical y
    const int n0   = ySlab * NPB;

    const int b   = tid & 63;
    const int cu  = __builtin_amdgcn_readfirstlane(tid >> 6);

    // ---- stage x tile: [64 b][96 floats], coalesced float4
    {
        const int XT4 = BTILE * (NPB * IN_DIM / 4);   // 1536
        for (int k = tid; k < XT4; k += NTHREADS) {
            int bb   = k / (NPB * 2);
            int off4 = k - bb * (NPB * 2);
            float4 v = *(const float4*)(x + ((size_t)(b0 + bb) * N_TOT + n0) * IN_DIM + off4 * 4);
            *(float4*)(&sh_x[bb * XR + off4 * 4]) = v;
        }
    }

    // ---- S fragment: all 16 d for (b, c)
    float S[OD];
    if (!FIRST) {
        const float4* sp = (const float4*)(S_acc + (size_t)(b0 + b) * CD + cu * OD);
        #pragma unroll
        for (int q = 0; q < 4; q++) ((float4*)S)[q] = sp[q];
    }

    float acc[OD];
    #pragma unroll
    for (int d = 0; d < OD; d++) acc[d] = 0.f;

    // Opaque zero in a VGPR: value is 0 at runtime but the compiler cannot
    // prove it, so W addresses become divergent -> vector loads, not s_load.
    int zz = 0;
    asm volatile("" : "+v"(zz));

    __syncthreads();   // sh_x ready

    const float* Wc = W + cu * OD + zz;    // divergent-looking base

    for (int nn = 0; nn < NPB; nn++) {
        float xf[IN_DIM];
        {
            const float4* xp = (const float4*)(&sh_x[b * XR + nn * IN_DIM]);
            ((float4*)xf)[0] = xp[0];
            ((float4*)xf)[1] = xp[1];
        }

        const float* Wn = Wc + (size_t)(n0 + nn) * (IN_DIM * CD);
        float u[OD];
        {
            const float4* wp = (const float4*)Wn;
            float4 w0 = wp[0], w1 = wp[1], w2 = wp[2], w3 = wp[3];
            const float* wf = (const float*)&w0;
            #pragma unroll
            for (int d = 0; d < 4;  d++) u[d]      = xf[0] * ((const float*)&w0)[d];
            #pragma unroll
            for (int d = 0; d < 4;  d++) u[4 + d]  = xf[0] * ((const float*)&w1)[d];
            #pragma unroll
            for (int d = 0; d < 4;  d++) u[8 + d]  = xf[0] * ((const float*)&w2)[d];
            #pragma unroll
            for (int d = 0; d < 4;  d++) u[12 + d] = xf[0] * ((const float*)&w3)[d];
            (void)wf;
        }
        #pragma unroll
        for (int i = 1; i < IN_DIM; i++) {
            const float4* wp = (const float4*)(Wn + i * CD);
            float4 w0 = wp[0], w1 = wp[1], w2 = wp[2], w3 = wp[3];
            #pragma unroll
            for (int d = 0; d < 4;  d++) u[d]      = fmaf(xf[i], ((const float*)&w0)[d], u[d]);
            #pragma unroll
            for (int d = 0; d < 4;  d++) u[4 + d]  = fmaf(xf[i], ((const float*)&w1)[d], u[4 + d]);
            #pragma unroll
            for (int d = 0; d < 4;  d++) u[8 + d]  = fmaf(xf[i], ((const float*)&w2)[d], u[8 + d]);
            #pragma unroll
            for (int d = 0; d < 4;  d++) u[12 + d] = fmaf(xf[i], ((const float*)&w3)[d], u[12 + d]);
        }

        if (!FIRST) {
            const int cur = nn & 1;
            float lg = 0.f;
            #pragma unroll
            for (int d = 0; d < OD; d++) lg = fmaf(u[d], S[d], lg);
            sh_lg[cur][cu * LB + b] = lg;
            __syncthreads();

            float m = -1e30f;
            float row[NC];
            #pragma unroll
            for (int k = 0; k < NC; k++) {
                row[k] = sh_lg[cur][k * LB + b];
                m = fmaxf(m, row[k]);
            }
            float den = 0.f;
            #pragma unroll
            for (int k = 0; k < NC; k++) den += __expf(row[k] - m);
            float cw = __expf(lg - m) / den;

            #pragma unroll
            for (int d = 0; d < OD; d++) acc[d] = fmaf(cw, u[d], acc[d]);
        } else {
            #pragma unroll
            for (int d = 0; d < OD; d++) acc[d] += u[d];
        }
    }

    float* dst = part + ((size_t)ySlab * B_TOT + (b0 + b)) * CD + cu * OD;
    #pragma unroll
    for (int q = 0; q < 4; q++)
        ((float4*)dst)[q] = ((float4*)acc)[q];
}

// ===== Full-device merged reduce: 1280 blocks × 256 threads = 5 blk/CU.
// Block owns 8 float4-columns; thread (col, grp) sums 6 slabs (y = grp+32k);
// LDS combine; threads 0..7 apply scale/bias + stage B:
// store S_acc (round 0 — no memset), add (round 1), squash -> v_out (round 2).
__global__ __launch_bounds__(256) void reduce_round(
    const float* __restrict__ part,   // [NS, B, 160]
    float* __restrict__ S_acc,        // [B, 160]
    float* __restrict__ v_out,        // [B, 10, 16]
    float scale, int round)
{
    __shared__ float4 sh[RGRPS][RCOLS];   // 4 KB

    const int col = threadIdx.x & (RCOLS - 1);
    const int grp = threadIdx.x >> 3;               // 0..31
    const int g   = blockIdx.x * RCOLS + col;       // float4 column index

    const float4* p4 = (const float4*)part + (size_t)grp * NF4 + g;
    float4 s = { 0.f, 0.f, 0.f, 0.f };
    #pragma unroll
    for (int y = 0; y < RYPER; y++) {               // slabs grp, grp+32, ...
        float4 t = p4[(size_t)y * RGRPS * NF4];
        s.x += t.x; s.y += t.y; s.z += t.z; s.w += t.w;
    }
    sh[grp][col] = s;
    __syncthreads();

    if (threadIdx.x < RCOLS) {
        float4 t = { 0.f, 0.f, 0.f, 0.f };
        #pragma unroll
        for (int k = 0; k < RGRPS; k++) {
            float4 q = sh[k][col];
            t.x += q.x; t.y += q.y; t.z += q.z; t.w += q.w;
        }
        t.x = t.x * scale + RBIAS;
        t.y = t.y * scale + RBIAS;
        t.z = t.z * scale + RBIAS;
        t.w = t.w * scale + RBIAS;

        if (round == 0) {
            ((float4*)S_acc)[g] = t;          // store — no memset required
        } else if (round == 1) {
            float4 o = ((float4*)S_acc)[g];
            o.x += t.x; o.y += t.y; o.z += t.z; o.w += t.w;
            ((float4*)S_acc)[g] = o;
        } else {
            // squash: 16 d = 4 consecutive float4 columns = lanes 4k..4k+3
            float ss = t.x * t.x + t.y * t.y + t.z * t.z + t.w * t.w;
            ss += __shfl_xor(ss, 1, 64);
            ss += __shfl_xor(ss, 2, 64);
            float norm = sqrtf(ss);
            float k2 = norm / (1.0f + ss);
            float4 v = { t.x * k2, t.y * k2, t.z * k2, t.w * k2 };
            ((float4*)v_out)[g] = v;
        }
    }
}

extern "C" void kernel_launch(void* const* d_in, const int* in_sizes, int n_in,
                              void* d_out, int out_size, void* d_ws, size_t ws_size,
                              hipStream_t stream) {
    const float* x = (const float*)d_in[0];   // [256,2304,8]
    const float* W = (const float*)d_in[1];   // [2304,8,160]
    float* out = (float*)d_out;               // [256,10,16]

    // Workspace (every byte written before read each call — re-poison safe)
    float* part  = (float*)d_ws;                            // NS * 40960  (~31.5 MB)
    float* S_acc = part + (size_t)NS * B_TOT * CD;          // 40960 floats

    const dim3 rgrid(B_TOT / BTILE, NS);
    const int  RG = NF4 / RCOLS;   // 1280 reduce blocks — 5/CU, balanced

    // Round 0 (uniform cw; 0.1 folded into reduce scale; S_acc stored not added)
    routing_round<1><<<rgrid, NTHREADS, 0, stream>>>(x, W, S_acc, part);
    reduce_round<<<RG, 256, 0, stream>>>(part, S_acc, out, 0.1f, 0);

    // Round 1
    routing_round<0><<<rgrid, NTHREADS, 0, stream>>>(x, W, S_acc, part);
    reduce_round<<<RG, 256, 0, stream>>>(part, S_acc, out, 1.0f, 1);

    // Round 2 (+final squash fused)
    routing_round<0><<<rgrid, NTHREADS, 0, stream>>>(x, W, S_acc, part);
    reduce_round<<<RG, 256, 0, stream>>>(part, S_acc, out, 1.0f, 2);
}

// Round 3
// 197.058 us; speedup vs baseline: 2.1883x; 2.1883x over previous
//
#include <hip/hip_runtime.h>
#include <math.h>

// Problem constants (fixed by reference)
#define B_TOT   256
#define N_TOT   2304
#define IN_DIM  8
#define NC      10      // NUM_CLASSES
#define OD      16      // OUT_DIM
#define CD      160     // NC*OD
#define RBIAS   0.1f

// R3 retile: grid = 512 blocks = exactly 2 blocks/CU (20 waves/CU).
// Paired blocks (same CU) process the SAME n-range with different b0 ->
// their scalar W cache lines coincide; unique K$ misses/CU/nn: 240 -> 80.
#define BTILE    64                      // b per block (= wave lanes)
#define NS       128                     // n-slices
#define NPB      (N_TOT / NS)            // 18 n per block
#define NTHREADS 640                     // 10 waves
#define XR       (NPB * IN_DIM + 4)      // 148: x row stride
#define LB       72                      // logit board row stride
#define NF4      (B_TOT * CD / 4)        // 10240 float4 per partial slab

#define NXCD     8

// Reduce: 1280 blocks × 256 thr = 5 blk/CU balanced
#define RCOLS    8                       // float4-columns per reduce block
#define RGRPS    32                      // y-groups per reduce block
#define RYPER    (NS / RGRPS)            // 4 slabs per (col, grp) thread

// ===== Routing round (R1's proven scalar-W body; R2's vector-W reverted).
// R3 change is pure index remap + NPB retile:
//   o = flat block id (0..511). xcd = o&7 (bid%8 -> XCD round-robin,
//   confirmed by R1's FETCH 55.5->21.4MB). Within-XCD rank r = o>>3
//   (0..63); breadth-first fill -> ranks r and r+32 co-reside on one CU.
//   Map: cuslot = r&31, pairid = r>>5; y = xcd*16 + (cuslot&15);
//   b0 = ((cuslot>>4)*2 + pairid)*64.
//   => the CU's two blocks share (y, n-range), differ in b0. All 20 waves
//   then hit the same 5120B of W per nn (80 lines) instead of 240 disjoint.
template <int FIRST>
__global__ __launch_bounds__(NTHREADS) void routing_round(
    const float* __restrict__ x,      // [B, N, 8]
    const float* __restrict__ W,      // [N, 8, 160]
    const float* __restrict__ S_acc,  // [B, 160]
    float* __restrict__ part)         // [NS, B, 160]
{
    __shared__ float sh_x[BTILE * XR];            // 37.9 KB
    __shared__ float sh_lg[2][NC * LB];           // 5.8 KB

    const int tid = threadIdx.x;

    const int o      = blockIdx.x;                 // 0..511
    const int xcd    = o & (NXCD - 1);
    const int r      = o >> 3;                     // 0..63 within-XCD rank
    const int cuslot = r & 31;
    const int pairid = r >> 5;                     // 0/1: the two blocks on a CU
    const int ySlab  = xcd * 16 + (cuslot & 15);   // 0..127
    const int b0     = ((cuslot >> 4) * 2 + pairid) * BTILE;
    const int n0     = ySlab * NPB;

    const int b   = tid & 63;
    const int cu  = __builtin_amdgcn_readfirstlane(tid >> 6);

    // ---- stage x tile: [64 b][144 floats], coalesced float4
    {
        const int XT4 = BTILE * (NPB * IN_DIM / 4);   // 2304
        for (int k = tid; k < XT4; k += NTHREADS) {
            int bb   = k / (NPB * 2);
            int off4 = k - bb * (NPB * 2);
            float4 v = *(const float4*)(x + ((size_t)(b0 + bb) * N_TOT + n0) * IN_DIM + off4 * 4);
            *(float4*)(&sh_x[bb * XR + off4 * 4]) = v;
        }
    }

    // ---- S fragment: all 16 d for (b, c)
    float S[OD];
    if (!FIRST) {
        const float4* sp = (const float4*)(S_acc + (size_t)(b0 + b) * CD + cu * OD);
        #pragma unroll
        for (int q = 0; q < 4; q++) ((float4*)S)[q] = sp[q];
    }

    float acc[OD];
    #pragma unroll
    for (int d = 0; d < OD; d++) acc[d] = 0.f;

    __syncthreads();   // sh_x ready

    const float* Wc = W + cu * OD;    // wave-uniform base -> scalar loads

    for (int nn = 0; nn < NPB; nn++) {
        float xf[IN_DIM];
        {
            const float4* xp = (const float4*)(&sh_x[b * XR + nn * IN_DIM]);
            ((float4*)xf)[0] = xp[0];
            ((float4*)xf)[1] = xp[1];
        }

        const float* Wn = Wc + (size_t)(n0 + nn) * (IN_DIM * CD);
        float u[OD];
        #pragma unroll
        for (int d = 0; d < OD; d++) u[d] = xf[0] * Wn[d];
        #pragma unroll
        for (int i = 1; i < IN_DIM; i++) {
            const float* Wi = Wn + i * CD;
            #pragma unroll
            for (int d = 0; d < OD; d++) u[d] = fmaf(xf[i], Wi[d], u[d]);
        }

        if (!FIRST) {
            const int cur = nn & 1;
            float lg = 0.f;
            #pragma unroll
            for (int d = 0; d < OD; d++) lg = fmaf(u[d], S[d], lg);
            sh_lg[cur][cu * LB + b] = lg;
            __syncthreads();

            float m = -1e30f;
            float row[NC];
            #pragma unroll
            for (int k = 0; k < NC; k++) {
                row[k] = sh_lg[cur][k * LB + b];
                m = fmaxf(m, row[k]);
            }
            float den = 0.f;
            #pragma unroll
            for (int k = 0; k < NC; k++) den += __expf(row[k] - m);
            float cw = __expf(lg - m) / den;

            #pragma unroll
            for (int d = 0; d < OD; d++) acc[d] = fmaf(cw, u[d], acc[d]);
        } else {
            #pragma unroll
            for (int d = 0; d < OD; d++) acc[d] += u[d];
        }
    }

    float* dst = part + ((size_t)ySlab * B_TOT + (b0 + b)) * CD + cu * OD;
    #pragma unroll
    for (int q = 0; q < 4; q++)
        ((float4*)dst)[q] = ((float4*)acc)[q];
}

// ===== Full-device merged reduce: 1280 blocks × 256 threads = 5 blk/CU.
// Block owns 8 float4-columns; thread (col, grp) sums 4 slabs (y = grp+32k);
// LDS combine; threads 0..7 apply scale/bias + stage B:
// store S_acc (round 0 — no memset), add (round 1), squash -> v_out (round 2).
__global__ __launch_bounds__(256) void reduce_round(
    const float* __restrict__ part,   // [NS, B, 160]
    float* __restrict__ S_acc,        // [B, 160]
    float* __restrict__ v_out,        // [B, 10, 16]
    float scale, int round)
{
    __shared__ float4 sh[RGRPS][RCOLS];   // 4 KB

    const int col = threadIdx.x & (RCOLS - 1);
    const int grp = threadIdx.x >> 3;               // 0..31
    const int g   = blockIdx.x * RCOLS + col;       // float4 column index

    const float4* p4 = (const float4*)part + (size_t)grp * NF4 + g;
    float4 s = { 0.f, 0.f, 0.f, 0.f };
    #pragma unroll
    for (int y = 0; y < RYPER; y++) {               // slabs grp, grp+32, ...
        float4 t = p4[(size_t)y * RGRPS * NF4];
        s.x += t.x; s.y += t.y; s.z += t.z; s.w += t.w;
    }
    sh[grp][col] = s;
    __syncthreads();

    if (threadIdx.x < RCOLS) {
        float4 t = { 0.f, 0.f, 0.f, 0.f };
        #pragma unroll
        for (int k = 0; k < RGRPS; k++) {
            float4 q = sh[k][col];
            t.x += q.x; t.y += q.y; t.z += q.z; t.w += q.w;
        }
        t.x = t.x * scale + RBIAS;
        t.y = t.y * scale + RBIAS;
        t.z = t.z * scale + RBIAS;
        t.w = t.w * scale + RBIAS;

        if (round == 0) {
            ((float4*)S_acc)[g] = t;          // store — no memset required
        } else if (round == 1) {
            float4 o = ((float4*)S_acc)[g];
            o.x += t.x; o.y += t.y; o.z += t.z; o.w += t.w;
            ((float4*)S_acc)[g] = o;
        } else {
            // squash: 16 d = 4 consecutive float4 columns = lanes 4k..4k+3
            float ss = t.x * t.x + t.y * t.y + t.z * t.z + t.w * t.w;
            ss += __shfl_xor(ss, 1, 64);
            ss += __shfl_xor(ss, 2, 64);
            float norm = sqrtf(ss);
            float k2 = norm / (1.0f + ss);
            float4 v = { t.x * k2, t.y * k2, t.z * k2, t.w * k2 };
            ((float4*)v_out)[g] = v;
        }
    }
}

extern "C" void kernel_launch(void* const* d_in, const int* in_sizes, int n_in,
                              void* d_out, int out_size, void* d_ws, size_t ws_size,
                              hipStream_t stream) {
    const float* x = (const float*)d_in[0];   // [256,2304,8]
    const float* W = (const float*)d_in[1];   // [2304,8,160]
    float* out = (float*)d_out;               // [256,10,16]

    // Workspace (every byte written before read each call — re-poison safe)
    float* part  = (float*)d_ws;                            // NS * 40960  (~21 MB)
    float* S_acc = part + (size_t)NS * B_TOT * CD;          // 40960 floats

    const dim3 rgrid(NS * (B_TOT / BTILE));   // 512 blocks, flat
    const int  RG = NF4 / RCOLS;              // 1280 reduce blocks — 5/CU

    // Round 0 (uniform cw; 0.1 folded into reduce scale; S_acc stored not added)
    routing_round<1><<<rgrid, NTHREADS, 0, stream>>>(x, W, S_acc, part);
    reduce_round<<<RG, 256, 0, stream>>>(part, S_acc, out, 0.1f, 0);

    // Round 1
    routing_round<0><<<rgrid, NTHREADS, 0, stream>>>(x, W, S_acc, part);
    reduce_round<<<RG, 256, 0, stream>>>(part, S_acc, out, 1.0f, 1);

    // Round 2 (+final squash fused)
    routing_round<0><<<rgrid, NTHREADS, 0, stream>>>(x, W, S_acc, part);
    reduce_round<<<RG, 256, 0, stream>>>(part, S_acc, out, 1.0f, 2);
}